// Round 1
// baseline (324.928 us; speedup 1.0000x reference)
//
// CAM+SE module, MI355X gfx950.
// R1: full pipeline — transpose+SE-pool / SE-MLP / energy GEMM (bf16 MFMA,
// reg-staged fp32->bf16, T2 swizzle) / fused rowmin-softmax / PV GEMM
// (global_load_lds + fused epilogue). energy scratch lives in d_out.
#include <hip/hip_runtime.h>
#include <cstdint>
#include <cstddef>

#define B_ 16
#define C_ 512
#define N_ 4096   // H*W
#define CH_ 64    // C/8

typedef __attribute__((ext_vector_type(8))) short short8;
typedef __attribute__((ext_vector_type(4))) float f32x4;

__device__ __forceinline__ unsigned short f2bf(float f) {
  union { float f; unsigned u; } v; v.f = f;
  unsigned r = v.u + 0x7FFFu + ((v.u >> 16) & 1u);   // RNE
  return (unsigned short)(r >> 16);
}
__device__ __forceinline__ ushort4 cvt4(float4 v) {
  ushort4 u; u.x = f2bf(v.x); u.y = f2bf(v.y); u.z = f2bf(v.z); u.w = f2bf(v.w);
  return u;
}
__device__ __forceinline__ void gload_lds16(const void* g, void* l) {
  __builtin_amdgcn_global_load_lds((__attribute__((address_space(1))) void*)g,
                                   (__attribute__((address_space(3))) void*)l,
                                   16, 0, 0);
}

// ---------------------------------------------------------------- K1:
// x (fp32 [B][C][N]) -> qT (bf16 [B][N][C]) transposed, + per-(b,c) partial
// sums over 64-col tiles for the SE mean.
__global__ __launch_bounds__(256) void k1_transpose(
    const float* __restrict__ x, unsigned short* __restrict__ qT,
    float* __restrict__ partial) {
  __shared__ alignas(16) unsigned short tile[64][72];  // [n_local][c_local], padded
  const int b = blockIdx.z, ct = blockIdx.y, nt = blockIdx.x;
  const int c0 = ct * 64, n0 = nt * 64;
  const int t = threadIdx.x;
  const int r = t >> 2, q = t & 3;       // r = c_local row, 4 threads/row
  const float* xr = x + ((size_t)(b * C_ + c0 + r)) * N_ + n0;
  float sum = 0.f;
#pragma unroll
  for (int j = 0; j < 4; ++j) {
    float4 v = *(const float4*)(xr + (q + 4 * j) * 4);
    sum += v.x + v.y + v.z + v.w;
    const int nb = (q + 4 * j) * 4;
    tile[nb + 0][r] = f2bf(v.x);
    tile[nb + 1][r] = f2bf(v.y);
    tile[nb + 2][r] = f2bf(v.z);
    tile[nb + 3][r] = f2bf(v.w);
  }
  sum += __shfl_xor(sum, 1);
  sum += __shfl_xor(sum, 2);
  if (q == 0) partial[((size_t)(b * C_ + c0 + r)) * 64 + nt] = sum;
  __syncthreads();
  // write qT rows: row n = n0+r, 4 threads x 16 bf16 = 64 c's
  unsigned short* qrow = qT + ((size_t)b * N_ + n0 + r) * C_ + c0 + q * 16;
  *(uint4*)(qrow)     = *(const uint4*)&tile[r][q * 16];
  *(uint4*)(qrow + 8) = *(const uint4*)&tile[r][q * 16 + 8];
}

// ---------------------------------------------------------------- K2:
// SE MLP: se = mean(x) -> relu(se@W1+b1) -> sigmoid(@W2+b2); gse = gamma*se.
__global__ __launch_bounds__(256) void k2_se(
    const float* __restrict__ partial, const float* __restrict__ gamma,
    const float* __restrict__ W1, const float* __restrict__ b1,
    const float* __restrict__ W2, const float* __restrict__ b2,
    float* __restrict__ gse) {
  __shared__ float se_s[C_];
  __shared__ float hp[4][CH_];
  __shared__ float h_s[CH_];
  const int b = blockIdx.x, t = threadIdx.x;
  for (int c = t; c < C_; c += 256) {
    const float* p = partial + ((size_t)(b * C_ + c)) * 64;
    float s = 0.f;
#pragma unroll
    for (int i = 0; i < 64; ++i) s += p[i];
    se_s[c] = s * (1.0f / (float)N_);
  }
  __syncthreads();
  {  // hidden: 4 segments of 128 c's per h
    const int h = t & 63, seg = t >> 6;
    float a = 0.f;
    const int cb = seg * 128;
    for (int c = cb; c < cb + 128; ++c) a += se_s[c] * W1[c * CH_ + h];
    hp[seg][h] = a;
  }
  __syncthreads();
  if (t < CH_) {
    float a = b1[t] + hp[0][t] + hp[1][t] + hp[2][t] + hp[3][t];
    h_s[t] = fmaxf(a, 0.f);
  }
  __syncthreads();
  const float g = gamma[0];
  for (int c = t; c < C_; c += 256) {
    float a = b2[c];
#pragma unroll
    for (int hh = 0; hh < CH_; ++hh) a += h_s[hh] * W2[hh * C_ + c];
    const float sig = 1.0f / (1.0f + __expf(-a));
    gse[b * C_ + c] = g * sig;
  }
}

// ---------------------------------------------------------------- K3:
// energy[b] = q qT (512x512, K=4096), bf16 MFMA, reg-staged fp32->bf16,
// 128x128 tile, BK=64, XOR-swizzled LDS (16B chunk ^ row&7).
__global__ __launch_bounds__(256) void k3_energy(const float* __restrict__ x,
                                                 float* __restrict__ energy) {
  __shared__ alignas(16) unsigned short As[128 * 64];
  __shared__ alignas(16) unsigned short Bs[128 * 64];
  const int b = blockIdx.z;
  const int d0 = blockIdx.x * 128, c0 = blockIdx.y * 128;
  const float* xb = x + (size_t)b * C_ * N_;
  const int t = threadIdx.x, l = t & 63, wid = t >> 6;
  const int wr = wid >> 1, wc = wid & 1;
  f32x4 acc[4][4];
#pragma unroll
  for (int m = 0; m < 4; ++m)
#pragma unroll
    for (int n = 0; n < 4; ++n) acc[m][n] = (f32x4){0.f, 0.f, 0.f, 0.f};

  for (int kt = 0; kt < 64; ++kt) {
    __syncthreads();
#pragma unroll
    for (int j = 0; j < 8; ++j) {
      const int f = t + 256 * j;          // 2048 float4 slots per tile
      const int row = f >> 4, col4 = f & 15;
      const int lofs = row * 128 + (((col4 >> 1) ^ (row & 7)) * 16) + (col4 & 1) * 8;
      float4 va = *(const float4*)(xb + (size_t)(c0 + row) * N_ + kt * 64 + col4 * 4);
      *(ushort4*)((char*)As + lofs) = cvt4(va);
      float4 vb = *(const float4*)(xb + (size_t)(d0 + row) * N_ + kt * 64 + col4 * 4);
      *(ushort4*)((char*)Bs + lofs) = cvt4(vb);
    }
    __syncthreads();
#pragma unroll
    for (int ks = 0; ks < 2; ++ks) {
      short8 af[4], bfv[4];
#pragma unroll
      for (int m = 0; m < 4; ++m) {
        const int row = wr * 64 + m * 16 + (l & 15);
        const int ch = (ks * 4 + (l >> 4)) ^ (row & 7);
        af[m] = *(const short8*)((const char*)As + row * 128 + ch * 16);
      }
#pragma unroll
      for (int n = 0; n < 4; ++n) {
        const int row = wc * 64 + n * 16 + (l & 15);
        const int ch = (ks * 4 + (l >> 4)) ^ (row & 7);
        bfv[n] = *(const short8*)((const char*)Bs + row * 128 + ch * 16);
      }
#pragma unroll
      for (int m = 0; m < 4; ++m)
#pragma unroll
        for (int n = 0; n < 4; ++n)
          acc[m][n] = __builtin_amdgcn_mfma_f32_16x16x32_bf16(af[m], bfv[n],
                                                              acc[m][n], 0, 0, 0);
    }
  }
  float* eb = energy + (size_t)b * C_ * C_;
#pragma unroll
  for (int m = 0; m < 4; ++m) {
    const int cb = c0 + wr * 64 + m * 16 + ((l >> 4) * 4);
#pragma unroll
    for (int n = 0; n < 4; ++n) {
      const int d = d0 + wc * 64 + n * 16 + (l & 15);
#pragma unroll
      for (int r = 0; r < 4; ++r)
        eb[(size_t)(cb + r) * C_ + d] = acc[m][n][r];
    }
  }
}

// ---------------------------------------------------------------- K4:
// att[c][d] = exp(rowmin_c - e[c][d]) / sum_d exp(rowmin_c - e[c][d])  (bf16).
// (softmax(max-e) == softmax(-e), stabilized by rowmin; exponents <= 0.)
__global__ __launch_bounds__(256) void k4_softmax(const float* __restrict__ energy,
                                                  unsigned short* __restrict__ att) {
  const int t = threadIdx.x, l = t & 63, wid = t >> 6;
  const size_t row = (size_t)blockIdx.x * 4 + wid;
  const float* er = energy + row * C_;
  float4 v0 = ((const float4*)er)[l];
  float4 v1 = ((const float4*)er)[64 + l];
  float mn = fminf(fminf(fminf(v0.x, v0.y), fminf(v0.z, v0.w)),
                   fminf(fminf(v1.x, v1.y), fminf(v1.z, v1.w)));
#pragma unroll
  for (int s = 1; s < 64; s <<= 1) mn = fminf(mn, __shfl_xor(mn, s));
  float e0 = __expf(mn - v0.x), e1 = __expf(mn - v0.y);
  float e2 = __expf(mn - v0.z), e3 = __expf(mn - v0.w);
  float e4 = __expf(mn - v1.x), e5 = __expf(mn - v1.y);
  float e6 = __expf(mn - v1.z), e7 = __expf(mn - v1.w);
  float sm = ((e0 + e1) + (e2 + e3)) + ((e4 + e5) + (e6 + e7));
#pragma unroll
  for (int s = 1; s < 64; s <<= 1) sm += __shfl_xor(sm, s);
  const float inv = 1.0f / sm;
  unsigned short* ar = att + row * C_;
  ushort4 u0, u1;
  u0.x = f2bf(e0 * inv); u0.y = f2bf(e1 * inv);
  u0.z = f2bf(e2 * inv); u0.w = f2bf(e3 * inv);
  u1.x = f2bf(e4 * inv); u1.y = f2bf(e5 * inv);
  u1.z = f2bf(e6 * inv); u1.w = f2bf(e7 * inv);
  *(ushort4*)(ar + 4 * l) = u0;
  *(ushort4*)(ar + 256 + 4 * l) = u1;
}

// ---------------------------------------------------------------- K5:
// D[c][n] = sum_d att[c][d] * q[d][n]  (A = att rows, Bt = qT rows),
// global_load_lds staging with pre-swizzled source, fused epilogue
// out = gse[c]*D + x.
__global__ __launch_bounds__(256) void k5_pv(
    const unsigned short* __restrict__ att, const unsigned short* __restrict__ qT,
    const float* __restrict__ gse, const float* __restrict__ x,
    float* __restrict__ out) {
  __shared__ alignas(16) unsigned short As[128 * 64];
  __shared__ alignas(16) unsigned short Bs[128 * 64];
  const int b = blockIdx.z;
  const int n0 = blockIdx.x * 128, c0 = blockIdx.y * 128;
  const int t = threadIdx.x, l = t & 63, wid = t >> 6;
  const int wr = wid >> 1, wc = wid & 1;
  const unsigned short* attb = att + (size_t)b * C_ * C_;
  const unsigned short* qTb = qT + (size_t)b * N_ * C_;
  f32x4 acc[4][4];
#pragma unroll
  for (int m = 0; m < 4; ++m)
#pragma unroll
    for (int n = 0; n < 4; ++n) acc[m][n] = (f32x4){0.f, 0.f, 0.f, 0.f};
  const int srow = l >> 3;   // row within 8-row chunk
  const int scc = l & 7;     // swizzled 16B-chunk slot
  for (int kt = 0; kt < 8; ++kt) {
#pragma unroll
    for (int i = 0; i < 4; ++i) {
      const int chunk = wid * 4 + i;         // 16 x 1KB chunks per tile
      const int row = chunk * 8 + srow;
      const int cc = scc ^ (row & 7);        // inverse-swizzled source chunk
      gload_lds16(attb + (size_t)(c0 + row) * C_ + kt * 64 + cc * 8,
                  (char*)As + chunk * 1024);
      gload_lds16(qTb + (size_t)(n0 + row) * C_ + kt * 64 + cc * 8,
                  (char*)Bs + chunk * 1024);
    }
    __syncthreads();
#pragma unroll
    for (int ks = 0; ks < 2; ++ks) {
      short8 af[4], bfv[4];
#pragma unroll
      for (int m = 0; m < 4; ++m) {
        const int row = wr * 64 + m * 16 + (l & 15);
        const int ch = (ks * 4 + (l >> 4)) ^ (row & 7);
        af[m] = *(const short8*)((const char*)As + row * 128 + ch * 16);
      }
#pragma unroll
      for (int n = 0; n < 4; ++n) {
        const int row = wc * 64 + n * 16 + (l & 15);
        const int ch = (ks * 4 + (l >> 4)) ^ (row & 7);
        bfv[n] = *(const short8*)((const char*)Bs + row * 128 + ch * 16);
      }
#pragma unroll
      for (int m = 0; m < 4; ++m)
#pragma unroll
        for (int n = 0; n < 4; ++n)
          acc[m][n] = __builtin_amdgcn_mfma_f32_16x16x32_bf16(af[m], bfv[n],
                                                              acc[m][n], 0, 0, 0);
    }
    __syncthreads();
  }
  // fused epilogue: out = gse[c] * D + x
  const float* xb = x + (size_t)b * C_ * N_;
  float* ob = out + (size_t)b * C_ * N_;
  const float* gseb = gse + b * C_;
#pragma unroll
  for (int m = 0; m < 4; ++m) {
    const int cb = c0 + wr * 64 + m * 16 + ((l >> 4) * 4);
#pragma unroll
    for (int r = 0; r < 4; ++r) {
      const int c = cb + r;
      const float g = gseb[c];
      const size_t base = (size_t)c * N_;
#pragma unroll
      for (int n = 0; n < 4; ++n) {
        const int nn = n0 + wc * 64 + n * 16 + (l & 15);
        ob[base + nn] = g * acc[m][n][r] + xb[base + nn];
      }
    }
  }
}

// ---------------------------------------------------------------- launch
extern "C" void kernel_launch(void* const* d_in, const int* in_sizes, int n_in,
                              void* d_out, int out_size, void* d_ws, size_t ws_size,
                              hipStream_t stream) {
  (void)in_sizes; (void)n_in; (void)out_size; (void)ws_size;
  const float* x     = (const float*)d_in[0];
  const float* gamma = (const float*)d_in[1];
  const float* W1    = (const float*)d_in[2];
  const float* b1    = (const float*)d_in[3];
  const float* W2    = (const float*)d_in[4];
  const float* b2    = (const float*)d_in[5];
  float* out = (float*)d_out;
  char* ws = (char*)d_ws;

  // workspace layout (~74 MiB)
  unsigned short* qT      = (unsigned short*)(ws);                 // 64 MiB
  unsigned short* att     = (unsigned short*)(ws + 67108864);      //  8 MiB
  float*          partial = (float*)(ws + 75497472);               //  2 MiB
  float*          gse     = (float*)(ws + 77594624);               // 32 KiB
  // energy (16 MiB) parked in d_out: read by K4 before K5 rewrites d_out.
  float* energy = out;

  k1_transpose<<<dim3(N_ / 64, C_ / 64, B_), dim3(256), 0, stream>>>(x, qT, partial);
  k2_se<<<dim3(B_), dim3(256), 0, stream>>>(partial, gamma, W1, b1, W2, b2, gse);
  k3_energy<<<dim3(C_ / 128, C_ / 128, B_), dim3(256), 0, stream>>>(x, energy);
  k4_softmax<<<dim3(B_ * C_ / 4), dim3(256), 0, stream>>>(energy, att);
  k5_pv<<<dim3(N_ / 128, C_ / 128, B_), dim3(256), 0, stream>>>(att, qT, gse, x, out);
}

// Round 2
// 265.940 us; speedup vs baseline: 1.2218x; 1.2218x over previous
//
// CAM+SE module, MI355X gfx950.
// R2: k3 energy GEMM rewritten — bf16 source (qbf produced by k1),
// global_load_lds staging, split-K=4 (1024 blocks, 4/CU), XCD-bijective
// swizzle (2 batches/XCD). Partial energies + qbf parked in d_out.
#include <hip/hip_runtime.h>
#include <cstdint>
#include <cstddef>

#define B_ 16
#define C_ 512
#define N_ 4096   // H*W
#define CH_ 64    // C/8

typedef __attribute__((ext_vector_type(8))) short short8;
typedef __attribute__((ext_vector_type(4))) float f32x4;

__device__ __forceinline__ unsigned short f2bf(float f) {
  union { float f; unsigned u; } v; v.f = f;
  unsigned r = v.u + 0x7FFFu + ((v.u >> 16) & 1u);   // RNE
  return (unsigned short)(r >> 16);
}
__device__ __forceinline__ ushort4 cvt4(float4 v) {
  ushort4 u; u.x = f2bf(v.x); u.y = f2bf(v.y); u.z = f2bf(v.z); u.w = f2bf(v.w);
  return u;
}
__device__ __forceinline__ void gload_lds16(const void* g, void* l) {
  __builtin_amdgcn_global_load_lds((__attribute__((address_space(1))) void*)g,
                                   (__attribute__((address_space(3))) void*)l,
                                   16, 0, 0);
}

// ---------------------------------------------------------------- K1:
// x (fp32 [B][C][N]) -> qT (bf16 [B][N][C]) transposed + qbf (bf16 [B][C][N])
// + per-(b,c) partial sums over 64-col tiles for the SE mean.
__global__ __launch_bounds__(256) void k1_transpose(
    const float* __restrict__ x, unsigned short* __restrict__ qT,
    unsigned short* __restrict__ qbf, float* __restrict__ partial) {
  __shared__ alignas(16) unsigned short tile[64][72];  // [n_local][c_local], padded
  const int b = blockIdx.z, ct = blockIdx.y, nt = blockIdx.x;
  const int c0 = ct * 64, n0 = nt * 64;
  const int t = threadIdx.x;
  const int r = t >> 2, q = t & 3;       // r = c_local row, 4 threads/row
  const float* xr = x + ((size_t)(b * C_ + c0 + r)) * N_ + n0;
  unsigned short* qbfr = qbf + ((size_t)(b * C_ + c0 + r)) * N_ + n0;
  float sum = 0.f;
#pragma unroll
  for (int j = 0; j < 4; ++j) {
    float4 v = *(const float4*)(xr + (q + 4 * j) * 4);
    sum += v.x + v.y + v.z + v.w;
    const int nb = (q + 4 * j) * 4;
    ushort4 u = cvt4(v);
    *(ushort4*)(qbfr + nb) = u;
    tile[nb + 0][r] = u.x;
    tile[nb + 1][r] = u.y;
    tile[nb + 2][r] = u.z;
    tile[nb + 3][r] = u.w;
  }
  sum += __shfl_xor(sum, 1);
  sum += __shfl_xor(sum, 2);
  if (q == 0) partial[((size_t)(b * C_ + c0 + r)) * 64 + nt] = sum;
  __syncthreads();
  // write qT rows: row n = n0+r, 4 threads x 16 bf16 = 64 c's
  unsigned short* qrow = qT + ((size_t)b * N_ + n0 + r) * C_ + c0 + q * 16;
  *(uint4*)(qrow)     = *(const uint4*)&tile[r][q * 16];
  *(uint4*)(qrow + 8) = *(const uint4*)&tile[r][q * 16 + 8];
}

// ---------------------------------------------------------------- K2:
// SE MLP: se = mean(x) -> relu(se@W1+b1) -> sigmoid(@W2+b2); gse = gamma*se.
__global__ __launch_bounds__(256) void k2_se(
    const float* __restrict__ partial, const float* __restrict__ gamma,
    const float* __restrict__ W1, const float* __restrict__ b1,
    const float* __restrict__ W2, const float* __restrict__ b2,
    float* __restrict__ gse) {
  __shared__ float se_s[C_];
  __shared__ float hp[4][CH_];
  __shared__ float h_s[CH_];
  const int b = blockIdx.x, t = threadIdx.x;
  for (int c = t; c < C_; c += 256) {
    const float* p = partial + ((size_t)(b * C_ + c)) * 64;
    float s = 0.f;
#pragma unroll
    for (int i = 0; i < 64; ++i) s += p[i];
    se_s[c] = s * (1.0f / (float)N_);
  }
  __syncthreads();
  {  // hidden: 4 segments of 128 c's per h
    const int h = t & 63, seg = t >> 6;
    float a = 0.f;
    const int cb = seg * 128;
    for (int c = cb; c < cb + 128; ++c) a += se_s[c] * W1[c * CH_ + h];
    hp[seg][h] = a;
  }
  __syncthreads();
  if (t < CH_) {
    float a = b1[t] + hp[0][t] + hp[1][t] + hp[2][t] + hp[3][t];
    h_s[t] = fmaxf(a, 0.f);
  }
  __syncthreads();
  const float g = gamma[0];
  for (int c = t; c < C_; c += 256) {
    float a = b2[c];
#pragma unroll
    for (int hh = 0; hh < CH_; ++hh) a += h_s[hh] * W2[hh * C_ + c];
    const float sig = 1.0f / (1.0f + __expf(-a));
    gse[b * C_ + c] = g * sig;
  }
}

// ---------------------------------------------------------------- K3:
// epartial[kc][b] += q qT over K-chunk of 1024 (bf16 MFMA, 128x128 tile,
// BK=64, global_load_lds w/ pre-swizzled source, XOR-swizzled LDS reads).
// Grid: 1024 blocks 1D, XCD-bijective swizzle -> 2 batches per XCD.
__global__ __launch_bounds__(256) void k3_energy(
    const unsigned short* __restrict__ qbf, float* __restrict__ epartial) {
  __shared__ alignas(16) unsigned short As[128 * 64];
  __shared__ alignas(16) unsigned short Bs[128 * 64];
  const int orig = blockIdx.x;
  const int wg = (orig & 7) * 128 + (orig >> 3);   // XCD x -> wg [x*128, x*128+128)
  const int b = wg >> 6;                            // 2 batches per XCD
  const int rem = wg & 63;
  const int kc = rem >> 4;                          // split-K chunk (0..3)
  const int tile = rem & 15;
  const int c0 = (tile >> 2) * 128, d0 = (tile & 3) * 128;
  const unsigned short* qb = qbf + (size_t)b * C_ * N_ + kc * 1024;
  const int t = threadIdx.x, l = t & 63, wid = t >> 6;
  const int wr = wid >> 1, wc = wid & 1;
  f32x4 acc[4][4];
#pragma unroll
  for (int m = 0; m < 4; ++m)
#pragma unroll
    for (int n = 0; n < 4; ++n) acc[m][n] = (f32x4){0.f, 0.f, 0.f, 0.f};
  const int srow = l >> 3;   // row within 8-row chunk
  const int scc = l & 7;     // swizzled 16B-chunk slot
  for (int kt = 0; kt < 16; ++kt) {
#pragma unroll
    for (int i = 0; i < 4; ++i) {
      const int chunk = wid * 4 + i;         // 16 x 1KB chunks per tile
      const int row = chunk * 8 + srow;
      const int cc = scc ^ (row & 7);        // inverse-swizzled source chunk
      gload_lds16(qb + (size_t)(c0 + row) * N_ + kt * 64 + cc * 8,
                  (char*)As + chunk * 1024);
      gload_lds16(qb + (size_t)(d0 + row) * N_ + kt * 64 + cc * 8,
                  (char*)Bs + chunk * 1024);
    }
    __syncthreads();
#pragma unroll
    for (int ks = 0; ks < 2; ++ks) {
      short8 af[4], bfv[4];
#pragma unroll
      for (int m = 0; m < 4; ++m) {
        const int row = wr * 64 + m * 16 + (l & 15);
        const int ch = (ks * 4 + (l >> 4)) ^ (row & 7);
        af[m] = *(const short8*)((const char*)As + row * 128 + ch * 16);
      }
#pragma unroll
      for (int n = 0; n < 4; ++n) {
        const int row = wc * 64 + n * 16 + (l & 15);
        const int ch = (ks * 4 + (l >> 4)) ^ (row & 7);
        bfv[n] = *(const short8*)((const char*)Bs + row * 128 + ch * 16);
      }
#pragma unroll
      for (int m = 0; m < 4; ++m)
#pragma unroll
        for (int n = 0; n < 4; ++n)
          acc[m][n] = __builtin_amdgcn_mfma_f32_16x16x32_bf16(af[m], bfv[n],
                                                              acc[m][n], 0, 0, 0);
    }
    __syncthreads();
  }
  float* eb = epartial + ((size_t)(kc * B_ + b)) * C_ * C_;
#pragma unroll
  for (int m = 0; m < 4; ++m) {
    const int cb = c0 + wr * 64 + m * 16 + ((l >> 4) * 4);
#pragma unroll
    for (int n = 0; n < 4; ++n) {
      const int d = d0 + wc * 64 + n * 16 + (l & 15);
#pragma unroll
      for (int r = 0; r < 4; ++r)
        eb[(size_t)(cb + r) * C_ + d] = acc[m][n][r];
    }
  }
}

// ---------------------------------------------------------------- K4:
// e[c][d] = sum_kc epartial; att = exp(rowmin - e)/sum (== softmax(max-e)).
__global__ __launch_bounds__(256) void k4_softmax(const float* __restrict__ ep,
                                                  unsigned short* __restrict__ att) {
  const int t = threadIdx.x, l = t & 63, wid = t >> 6;
  const size_t row = (size_t)blockIdx.x * 4 + wid;   // row in [0, B_*C_)
  f32x4 v0 = (f32x4){0.f, 0.f, 0.f, 0.f}, v1 = v0;
#pragma unroll
  for (int k = 0; k < 4; ++k) {
    const f32x4* er = (const f32x4*)(ep + ((size_t)k * B_ * C_ + row) * C_);
    v0 += er[l];
    v1 += er[64 + l];
  }
  float mn = fminf(fminf(fminf(v0[0], v0[1]), fminf(v0[2], v0[3])),
                   fminf(fminf(v1[0], v1[1]), fminf(v1[2], v1[3])));
#pragma unroll
  for (int s = 1; s < 64; s <<= 1) mn = fminf(mn, __shfl_xor(mn, s));
  float e0 = __expf(mn - v0[0]), e1 = __expf(mn - v0[1]);
  float e2 = __expf(mn - v0[2]), e3 = __expf(mn - v0[3]);
  float e4 = __expf(mn - v1[0]), e5 = __expf(mn - v1[1]);
  float e6 = __expf(mn - v1[2]), e7 = __expf(mn - v1[3]);
  float sm = ((e0 + e1) + (e2 + e3)) + ((e4 + e5) + (e6 + e7));
#pragma unroll
  for (int s = 1; s < 64; s <<= 1) sm += __shfl_xor(sm, s);
  const float inv = 1.0f / sm;
  unsigned short* ar = att + row * C_;
  ushort4 u0, u1;
  u0.x = f2bf(e0 * inv); u0.y = f2bf(e1 * inv);
  u0.z = f2bf(e2 * inv); u0.w = f2bf(e3 * inv);
  u1.x = f2bf(e4 * inv); u1.y = f2bf(e5 * inv);
  u1.z = f2bf(e6 * inv); u1.w = f2bf(e7 * inv);
  *(ushort4*)(ar + 4 * l) = u0;
  *(ushort4*)(ar + 256 + 4 * l) = u1;
}

// ---------------------------------------------------------------- K5:
// D[c][n] = sum_d att[c][d] * q[d][n]  (A = att rows, B = qT rows),
// global_load_lds staging with pre-swizzled source, fused epilogue
// out = gse[c]*D + x.
__global__ __launch_bounds__(256) void k5_pv(
    const unsigned short* __restrict__ att, const unsigned short* __restrict__ qT,
    const float* __restrict__ gse, const float* __restrict__ x,
    float* __restrict__ out) {
  __shared__ alignas(16) unsigned short As[128 * 64];
  __shared__ alignas(16) unsigned short Bs[128 * 64];
  const int b = blockIdx.z;
  const int n0 = blockIdx.x * 128, c0 = blockIdx.y * 128;
  const int t = threadIdx.x, l = t & 63, wid = t >> 6;
  const int wr = wid >> 1, wc = wid & 1;
  const unsigned short* attb = att + (size_t)b * C_ * C_;
  const unsigned short* qTb = qT + (size_t)b * N_ * C_;
  f32x4 acc[4][4];
#pragma unroll
  for (int m = 0; m < 4; ++m)
#pragma unroll
    for (int n = 0; n < 4; ++n) acc[m][n] = (f32x4){0.f, 0.f, 0.f, 0.f};
  const int srow = l >> 3;   // row within 8-row chunk
  const int scc = l & 7;     // swizzled 16B-chunk slot
  for (int kt = 0; kt < 8; ++kt) {
#pragma unroll
    for (int i = 0; i < 4; ++i) {
      const int chunk = wid * 4 + i;         // 16 x 1KB chunks per tile
      const int row = chunk * 8 + srow;
      const int cc = scc ^ (row & 7);        // inverse-swizzled source chunk
      gload_lds16(attb + (size_t)(c0 + row) * C_ + kt * 64 + cc * 8,
                  (char*)As + chunk * 1024);
      gload_lds16(qTb + (size_t)(n0 + row) * C_ + kt * 64 + cc * 8,
                  (char*)Bs + chunk * 1024);
    }
    __syncthreads();
#pragma unroll
    for (int ks = 0; ks < 2; ++ks) {
      short8 af[4], bfv[4];
#pragma unroll
      for (int m = 0; m < 4; ++m) {
        const int row = wr * 64 + m * 16 + (l & 15);
        const int ch = (ks * 4 + (l >> 4)) ^ (row & 7);
        af[m] = *(const short8*)((const char*)As + row * 128 + ch * 16);
      }
#pragma unroll
      for (int n = 0; n < 4; ++n) {
        const int row = wc * 64 + n * 16 + (l & 15);
        const int ch = (ks * 4 + (l >> 4)) ^ (row & 7);
        bfv[n] = *(const short8*)((const char*)Bs + row * 128 + ch * 16);
      }
#pragma unroll
      for (int m = 0; m < 4; ++m)
#pragma unroll
        for (int n = 0; n < 4; ++n)
          acc[m][n] = __builtin_amdgcn_mfma_f32_16x16x32_bf16(af[m], bfv[n],
                                                              acc[m][n], 0, 0, 0);
    }
    __syncthreads();
  }
  // fused epilogue: out = gse[c] * D + x
  const float* xb = x + (size_t)b * C_ * N_;
  float* ob = out + (size_t)b * C_ * N_;
  const float* gseb = gse + b * C_;
#pragma unroll
  for (int m = 0; m < 4; ++m) {
    const int cb = c0 + wr * 64 + m * 16 + ((l >> 4) * 4);
#pragma unroll
    for (int r = 0; r < 4; ++r) {
      const int c = cb + r;
      const float g = gseb[c];
      const size_t base = (size_t)c * N_;
#pragma unroll
      for (int n = 0; n < 4; ++n) {
        const int nn = n0 + wc * 64 + n * 16 + (l & 15);
        ob[base + nn] = g * acc[m][n][r] + xb[base + nn];
      }
    }
  }
}

// ---------------------------------------------------------------- launch
extern "C" void kernel_launch(void* const* d_in, const int* in_sizes, int n_in,
                              void* d_out, int out_size, void* d_ws, size_t ws_size,
                              hipStream_t stream) {
  (void)in_sizes; (void)n_in; (void)out_size; (void)ws_size;
  const float* x     = (const float*)d_in[0];
  const float* gamma = (const float*)d_in[1];
  const float* W1    = (const float*)d_in[2];
  const float* b1    = (const float*)d_in[3];
  const float* W2    = (const float*)d_in[4];
  const float* b2    = (const float*)d_in[5];
  float* out = (float*)d_out;
  char* ws = (char*)d_ws;

  // workspace layout (~74 MiB)
  unsigned short* qT      = (unsigned short*)(ws);                 // 64 MiB
  unsigned short* att     = (unsigned short*)(ws + 67108864);      //  8 MiB
  float*          partial = (float*)(ws + 75497472);               //  2 MiB
  float*          gse     = (float*)(ws + 77594624);               // 32 KiB
  // d_out parking (both fully written before k5 rewrites d_out):
  //   [0, 64 MiB):  epartial fp32 [4][B][C][C]   (written k3, read k4)
  //   [64,128 MiB): qbf bf16 [B][C][N]           (written k1, read k3)
  float*          epartial = out;
  unsigned short* qbf      = (unsigned short*)((char*)d_out + 67108864);

  k1_transpose<<<dim3(N_ / 64, C_ / 64, B_), dim3(256), 0, stream>>>(x, qT, qbf, partial);
  k2_se<<<dim3(B_), dim3(256), 0, stream>>>(partial, gamma, W1, b1, W2, b2, gse);
  k3_energy<<<dim3(1024), dim3(256), 0, stream>>>(qbf, epartial);
  k4_softmax<<<dim3(B_ * C_ / 4), dim3(256), 0, stream>>>(epartial, att);
  k5_pv<<<dim3(N_ / 128, C_ / 128, B_), dim3(256), 0, stream>>>(att, qT, gse, x, out);
}

// Round 4
// 241.682 us; speedup vs baseline: 1.3444x; 1.1004x over previous
//
// CAM+SE module, MI355X gfx950.
// R4: R3 with the k3 upper-triangle tile decoder fixed (j = tid-3 for i=1;
// was tid-2 -> j=4 OOB -> memory fault). Everything else identical to R3.
#include <hip/hip_runtime.h>
#include <cstdint>
#include <cstddef>

#define B_ 16
#define C_ 512
#define N_ 4096   // H*W
#define CH_ 64    // C/8

typedef __attribute__((ext_vector_type(8))) short short8;
typedef __attribute__((ext_vector_type(4))) float f32x4;

__device__ __forceinline__ unsigned short f2bf(float f) {
  union { float f; unsigned u; } v; v.f = f;
  unsigned r = v.u + 0x7FFFu + ((v.u >> 16) & 1u);   // RNE
  return (unsigned short)(r >> 16);
}
__device__ __forceinline__ ushort4 cvt4(float4 v) {
  ushort4 u; u.x = f2bf(v.x); u.y = f2bf(v.y); u.z = f2bf(v.z); u.w = f2bf(v.w);
  return u;
}
__device__ __forceinline__ void gload_lds16(const void* g, void* l) {
  __builtin_amdgcn_global_load_lds((__attribute__((address_space(1))) void*)g,
                                   (__attribute__((address_space(3))) void*)l,
                                   16, 0, 0);
}

// Stage one 128x64 bf16 tile pair into LDS (16 x 1KB chunks each), source
// pre-swizzled so LDS-linear dest + XOR-swizzled read match (rule #21).
__device__ __forceinline__ void stage_pair(
    const unsigned short* __restrict__ Asrc, const unsigned short* __restrict__ Bsrc,
    char* Adst, char* Bdst, int t, int ko, bool doB) {
  const int l = t & 63, wid = t >> 6;
  const int srow = l >> 3, scc = l & 7;
#pragma unroll
  for (int i = 0; i < 4; ++i) {
    const int chunk = wid * 4 + i;
    const int row = chunk * 8 + srow;
    const int cc = scc ^ (row & 7);
    gload_lds16(Asrc + (size_t)row * N_ + ko + cc * 8, Adst + chunk * 1024);
    if (doB)
      gload_lds16(Bsrc + (size_t)row * N_ + ko + cc * 8, Bdst + chunk * 1024);
  }
}
// Same but stride C_ (for att / qT tiles in k5).
__device__ __forceinline__ void stage_pair_c(
    const unsigned short* __restrict__ Asrc, const unsigned short* __restrict__ Bsrc,
    char* Adst, char* Bdst, int t, int ko) {
  const int l = t & 63, wid = t >> 6;
  const int srow = l >> 3, scc = l & 7;
#pragma unroll
  for (int i = 0; i < 4; ++i) {
    const int chunk = wid * 4 + i;
    const int row = chunk * 8 + srow;
    const int cc = scc ^ (row & 7);
    gload_lds16(Asrc + (size_t)row * C_ + ko + cc * 8, Adst + chunk * 1024);
    gload_lds16(Bsrc + (size_t)row * C_ + ko + cc * 8, Bdst + chunk * 1024);
  }
}

// One BK=64 K-step: A-operand rows from Abase (wave half wA), B-operand rows
// from Bbase (wave half wB). acc[m][n][r]: A-row = wA*64+m*16+(l>>4)*4+r,
// B-row = wB*64+n*16+(l&15).
__device__ __forceinline__ void gemm_step(const char* Abase, const char* Bbase,
                                          int l, int wA, int wB,
                                          f32x4 (&acc)[4][4]) {
#pragma unroll
  for (int ks = 0; ks < 2; ++ks) {
    short8 af[4], bfv[4];
#pragma unroll
    for (int m = 0; m < 4; ++m) {
      const int row = wA * 64 + m * 16 + (l & 15);
      const int ch = (ks * 4 + (l >> 4)) ^ (row & 7);
      af[m] = *(const short8*)(Abase + row * 128 + ch * 16);
    }
#pragma unroll
    for (int n = 0; n < 4; ++n) {
      const int row = wB * 64 + n * 16 + (l & 15);
      const int ch = (ks * 4 + (l >> 4)) ^ (row & 7);
      bfv[n] = *(const short8*)(Bbase + row * 128 + ch * 16);
    }
#pragma unroll
    for (int m = 0; m < 4; ++m)
#pragma unroll
      for (int n = 0; n < 4; ++n)
        acc[m][n] = __builtin_amdgcn_mfma_f32_16x16x32_bf16(af[m], bfv[n],
                                                            acc[m][n], 0, 0, 0);
  }
}

// ---------------------------------------------------------------- K1:
// x (fp32 [B][C][N]) -> qT (bf16 [B][N][C]) transposed + qbf (bf16 [B][C][N])
// + per-(b,c) partial sums over 64-col tiles for the SE mean.
__global__ __launch_bounds__(256) void k1_transpose(
    const float* __restrict__ x, unsigned short* __restrict__ qT,
    unsigned short* __restrict__ qbf, float* __restrict__ partial) {
  __shared__ alignas(16) unsigned short tile[64][72];
  const int b = blockIdx.z, ct = blockIdx.y, nt = blockIdx.x;
  const int c0 = ct * 64, n0 = nt * 64;
  const int t = threadIdx.x;
  const int r = t >> 2, q = t & 3;
  const float* xr = x + ((size_t)(b * C_ + c0 + r)) * N_ + n0;
  unsigned short* qbfr = qbf + ((size_t)(b * C_ + c0 + r)) * N_ + n0;
  float sum = 0.f;
#pragma unroll
  for (int j = 0; j < 4; ++j) {
    float4 v = *(const float4*)(xr + (q + 4 * j) * 4);
    sum += v.x + v.y + v.z + v.w;
    const int nb = (q + 4 * j) * 4;
    ushort4 u = cvt4(v);
    *(ushort4*)(qbfr + nb) = u;
    tile[nb + 0][r] = u.x;
    tile[nb + 1][r] = u.y;
    tile[nb + 2][r] = u.z;
    tile[nb + 3][r] = u.w;
  }
  sum += __shfl_xor(sum, 1);
  sum += __shfl_xor(sum, 2);
  if (q == 0) partial[((size_t)(b * C_ + c0 + r)) * 64 + nt] = sum;
  __syncthreads();
  unsigned short* qrow = qT + ((size_t)b * N_ + n0 + r) * C_ + c0 + q * 16;
  *(uint4*)(qrow)     = *(const uint4*)&tile[r][q * 16];
  *(uint4*)(qrow + 8) = *(const uint4*)&tile[r][q * 16 + 8];
}

// ---------------------------------------------------------------- K2: SE MLP
__global__ __launch_bounds__(256) void k2_se(
    const float* __restrict__ partial, const float* __restrict__ gamma,
    const float* __restrict__ W1, const float* __restrict__ b1,
    const float* __restrict__ W2, const float* __restrict__ b2,
    float* __restrict__ gse) {
  __shared__ float se_s[C_];
  __shared__ float hp[4][CH_];
  __shared__ float h_s[CH_];
  const int b = blockIdx.x, t = threadIdx.x;
  for (int c = t; c < C_; c += 256) {
    const float* p = partial + ((size_t)(b * C_ + c)) * 64;
    float s = 0.f;
#pragma unroll
    for (int i = 0; i < 64; ++i) s += p[i];
    se_s[c] = s * (1.0f / (float)N_);
  }
  __syncthreads();
  {
    const int h = t & 63, seg = t >> 6;
    float a = 0.f;
    const int cb = seg * 128;
    for (int c = cb; c < cb + 128; ++c) a += se_s[c] * W1[c * CH_ + h];
    hp[seg][h] = a;
  }
  __syncthreads();
  if (t < CH_) {
    float a = b1[t] + hp[0][t] + hp[1][t] + hp[2][t] + hp[3][t];
    h_s[t] = fmaxf(a, 0.f);
  }
  __syncthreads();
  const float g = gamma[0];
  for (int c = t; c < C_; c += 256) {
    float a = b2[c];
#pragma unroll
    for (int hh = 0; hh < CH_; ++hh) a += h_s[hh] * W2[hh * C_ + c];
    const float sig = 1.0f / (1.0f + __expf(-a));
    gse[b * C_ + c] = g * sig;
  }
}

// ---------------------------------------------------------------- K3:
// epartial[kc][b] = q q^T over K-chunk 1024. Symmetric: only 10 upper-tri
// 128^2 tiles; off-diag tiles mirror-write via a second LDS pass; diag tiles
// stage one panel. Double-buffered prefetch, 1 barrier per kt.
__global__ __launch_bounds__(256) void k3_energy(
    const unsigned short* __restrict__ qbf, float* __restrict__ ep) {
  __shared__ alignas(16) char lds[65536];   // dbuf staging, then f32 epilogue
  const int orig = blockIdx.x;
  const int wg = (orig & 7) * 80 + (orig >> 3);   // 640 = 8 x 80 bijective
  const int b = wg / 40;
  const int rem = wg % 40;
  const int kc = rem / 10;
  const int tid = rem % 10;
  int i, j;   // upper-triangle tile coords: (0,0..3),(1,1..3),(2,2..3),(3,3)
  if (tid < 4)      { i = 0; j = tid; }
  else if (tid < 7) { i = 1; j = tid - 3; }
  else if (tid < 9) { i = 2; j = tid - 5; }
  else              { i = 3; j = 3; }
  const int c0 = i * 128, d0 = j * 128;
  const bool diag = (i == j);
  const unsigned short* qb = qbf + (size_t)b * C_ * N_ + kc * 1024;
  const int t = threadIdx.x, l = t & 63, wid = t >> 6;
  const int wd = wid >> 1, wcc = wid & 1;
  f32x4 acc[4][4];   // [d-frag][c-frag]
#pragma unroll
  for (int m = 0; m < 4; ++m)
#pragma unroll
    for (int n = 0; n < 4; ++n) acc[m][n] = (f32x4){0.f, 0.f, 0.f, 0.f};
  char* A0 = lds;             char* B0 = lds + 16384;
  char* A1 = lds + 32768;     char* B1 = lds + 49152;
  const char* Bd0 = diag ? A0 : B0;   // diag: B-operand reads the A panel
  const char* Bd1 = diag ? A1 : B1;
  const unsigned short* cp = qb + (size_t)c0 * N_;   // c-panel rows
  const unsigned short* dp = qb + (size_t)d0 * N_;   // d-panel rows

  stage_pair(cp, dp, A0, B0, t, 0, !diag);
  __syncthreads();
  for (int kt2 = 0; kt2 < 8; ++kt2) {
    stage_pair(cp, dp, A1, B1, t, (2 * kt2 + 1) * 64, !diag);
    gemm_step(Bd0, A0, l, wd, wcc, acc);   // A-op = d-rows, B-op = c-rows
    __syncthreads();
    if (kt2 < 7) stage_pair(cp, dp, A0, B0, t, (2 * kt2 + 2) * 64, !diag);
    gemm_step(Bd1, A1, l, wd, wcc, acc);
    __syncthreads();
  }

  // Epilogue pass A: LDS[c][d] (float4 along d), then coalesced eb rows.
  float* Lf = (float*)lds;
  float* eb = ep + ((size_t)(kc * B_ + b)) * C_ * C_;
#pragma unroll
  for (int df = 0; df < 4; ++df)
#pragma unroll
    for (int cf = 0; cf < 4; ++cf) {
      const int c_l = wcc * 64 + cf * 16 + (l & 15);
      const int d4 = wd * 64 + df * 16 + ((l >> 4) << 2);
      *(float4*)&Lf[c_l * 128 + (d4 ^ ((c_l & 7) << 2))] =
          *(const float4*)&acc[df][cf];
    }
  __syncthreads();
#pragma unroll
  for (int jj = 0; jj < 16; ++jj) {
    const int row = jj * 8 + (t >> 5);
    const int col4 = (t & 31) * 4;
    float4 v = *(const float4*)&Lf[row * 128 + (col4 ^ ((row & 7) << 2))];
    *(float4*)&eb[(size_t)(c0 + row) * C_ + d0 + col4] = v;
  }
  if (!diag) {   // mirror block: LDS[d][c] (scalar), then coalesced rows
    __syncthreads();
#pragma unroll
    for (int df = 0; df < 4; ++df)
#pragma unroll
      for (int cf = 0; cf < 4; ++cf) {
        const int c_l = wcc * 64 + cf * 16 + (l & 15);
#pragma unroll
        for (int r = 0; r < 4; ++r) {
          const int d_l = wd * 64 + df * 16 + ((l >> 4) << 2) + r;
          Lf[d_l * 128 + (c_l ^ ((d_l & 7) << 2))] = acc[df][cf][r];
        }
      }
    __syncthreads();
#pragma unroll
    for (int jj = 0; jj < 16; ++jj) {
      const int row = jj * 8 + (t >> 5);
      const int col4 = (t & 31) * 4;
      float4 v = *(const float4*)&Lf[row * 128 + (col4 ^ ((row & 7) << 2))];
      *(float4*)&eb[(size_t)(d0 + row) * C_ + c0 + col4] = v;
    }
  }
}

// ---------------------------------------------------------------- K4:
// e = sum_kc epartial; att = exp(rowmin - e)/sum (== softmax(max-e)), bf16.
__global__ __launch_bounds__(256) void k4_softmax(const float* __restrict__ ep,
                                                  unsigned short* __restrict__ att) {
  const int t = threadIdx.x, l = t & 63, wid = t >> 6;
  const size_t row = (size_t)blockIdx.x * 4 + wid;
  f32x4 v0 = (f32x4){0.f, 0.f, 0.f, 0.f}, v1 = v0;
#pragma unroll
  for (int k = 0; k < 4; ++k) {
    const f32x4* er = (const f32x4*)(ep + ((size_t)k * B_ * C_ + row) * C_);
    v0 += er[l];
    v1 += er[64 + l];
  }
  float mn = fminf(fminf(fminf(v0[0], v0[1]), fminf(v0[2], v0[3])),
                   fminf(fminf(v1[0], v1[1]), fminf(v1[2], v1[3])));
#pragma unroll
  for (int s = 1; s < 64; s <<= 1) mn = fminf(mn, __shfl_xor(mn, s));
  float e0 = __expf(mn - v0[0]), e1 = __expf(mn - v0[1]);
  float e2 = __expf(mn - v0[2]), e3 = __expf(mn - v0[3]);
  float e4 = __expf(mn - v1[0]), e5 = __expf(mn - v1[1]);
  float e6 = __expf(mn - v1[2]), e7 = __expf(mn - v1[3]);
  float sm = ((e0 + e1) + (e2 + e3)) + ((e4 + e5) + (e6 + e7));
#pragma unroll
  for (int s = 1; s < 64; s <<= 1) sm += __shfl_xor(sm, s);
  const float inv = 1.0f / sm;
  unsigned short* ar = att + row * C_;
  ushort4 u0, u1;
  u0.x = f2bf(e0 * inv); u0.y = f2bf(e1 * inv);
  u0.z = f2bf(e2 * inv); u0.w = f2bf(e3 * inv);
  u1.x = f2bf(e4 * inv); u1.y = f2bf(e5 * inv);
  u1.z = f2bf(e6 * inv); u1.w = f2bf(e7 * inv);
  *(ushort4*)(ar + 4 * l) = u0;
  *(ushort4*)(ar + 256 + 4 * l) = u1;
}

// ---------------------------------------------------------------- K5:
// D[c][n] = att[c][:] . q[:][n]; dbuf prefetch; MFMA with A-op = qT n-rows
// so acc r-dim = n (float4-friendly); LDS-transpose epilogue:
// out[c][n0..] = gse[c]*D + x as float4 streams.
__global__ __launch_bounds__(256) void k5_pv(
    const unsigned short* __restrict__ att, const unsigned short* __restrict__ qT,
    const float* __restrict__ gse, const float* __restrict__ x,
    float* __restrict__ out) {
  __shared__ alignas(16) char lds[65536];
  const int orig = blockIdx.x;
  const int wg = (orig & 7) * 256 + (orig >> 3);   // 2048 = 8 x 256 bijective
  const int b = wg >> 7;                            // 2 batches per XCD
  const int rem = wg & 127;
  const int c0 = (rem >> 5) * 128, n0 = (rem & 31) * 128;
  const int t = threadIdx.x, l = t & 63, wid = t >> 6;
  const int wn = wid >> 1, wcc = wid & 1;
  const unsigned short* ap = att + (size_t)b * C_ * C_ + (size_t)c0 * C_;
  const unsigned short* qp = qT + (size_t)b * N_ * C_ + (size_t)n0 * C_;
  f32x4 acc[4][4];   // [n-frag][c-frag]
#pragma unroll
  for (int m = 0; m < 4; ++m)
#pragma unroll
    for (int n = 0; n < 4; ++n) acc[m][n] = (f32x4){0.f, 0.f, 0.f, 0.f};
  char* A0 = lds;             char* B0 = lds + 16384;
  char* A1 = lds + 32768;     char* B1 = lds + 49152;

  stage_pair_c(ap, qp, A0, B0, t, 0);
  __syncthreads();
  for (int kt2 = 0; kt2 < 4; ++kt2) {
    stage_pair_c(ap, qp, A1, B1, t, (2 * kt2 + 1) * 64);
    gemm_step(B0, A0, l, wn, wcc, acc);   // A-op = qT n-rows, B-op = att c-rows
    __syncthreads();
    if (kt2 < 3) stage_pair_c(ap, qp, A0, B0, t, (2 * kt2 + 2) * 64);
    gemm_step(B1, A1, l, wn, wcc, acc);
    __syncthreads();
  }

  // Epilogue: LDS[c][n] (float4 along n), then fused coalesced rows.
  float* Lf = (float*)lds;
#pragma unroll
  for (int nf = 0; nf < 4; ++nf)
#pragma unroll
    for (int cf = 0; cf < 4; ++cf) {
      const int c_l = wcc * 64 + cf * 16 + (l & 15);
      const int n4 = wn * 64 + nf * 16 + ((l >> 4) << 2);
      *(float4*)&Lf[c_l * 128 + (n4 ^ ((c_l & 7) << 2))] =
          *(const float4*)&acc[nf][cf];
    }
  __syncthreads();
  const float* xb = x + (size_t)b * C_ * N_;
  float* ob = out + (size_t)b * C_ * N_;
  const float* gseb = gse + b * C_;
#pragma unroll
  for (int jj = 0; jj < 16; ++jj) {
    const int row = jj * 8 + (t >> 5);
    const int col4 = (t & 31) * 4;
    const int c = c0 + row;
    const float g = gseb[c];
    float4 v = *(const float4*)&Lf[row * 128 + (col4 ^ ((row & 7) << 2))];
    const size_t gofs = (size_t)c * N_ + n0 + col4;
    float4 xv = *(const float4*)(xb + gofs);
    float4 ov;
    ov.x = g * v.x + xv.x; ov.y = g * v.y + xv.y;
    ov.z = g * v.z + xv.z; ov.w = g * v.w + xv.w;
    *(float4*)(ob + gofs) = ov;
  }
}

// ---------------------------------------------------------------- launch
extern "C" void kernel_launch(void* const* d_in, const int* in_sizes, int n_in,
                              void* d_out, int out_size, void* d_ws, size_t ws_size,
                              hipStream_t stream) {
  (void)in_sizes; (void)n_in; (void)out_size; (void)ws_size;
  const float* x     = (const float*)d_in[0];
  const float* gamma = (const float*)d_in[1];
  const float* W1    = (const float*)d_in[2];
  const float* b1    = (const float*)d_in[3];
  const float* W2    = (const float*)d_in[4];
  const float* b2    = (const float*)d_in[5];
  float* out = (float*)d_out;
  char* ws = (char*)d_ws;

  // workspace layout (~74 MiB)
  unsigned short* qT      = (unsigned short*)(ws);                 // 64 MiB
  unsigned short* att     = (unsigned short*)(ws + 67108864);      //  8 MiB
  float*          partial = (float*)(ws + 75497472);               //  2 MiB
  float*          gse     = (float*)(ws + 77594624);               // 32 KiB
  // d_out parking (dead before k5 rewrites d_out):
  //   [0, 64 MiB):  epartial fp32 [4][B][C][C]  (k3 -> k4)
  //   [64,128 MiB): qbf bf16 [B][C][N]          (k1 -> k3)
  float*          epartial = out;
  unsigned short* qbf      = (unsigned short*)((char*)d_out + 67108864);

  k1_transpose<<<dim3(N_ / 64, C_ / 64, B_), dim3(256), 0, stream>>>(x, qT, qbf, partial);
  k2_se<<<dim3(B_), dim3(256), 0, stream>>>(partial, gamma, W1, b1, W2, b2, gse);
  k3_energy<<<dim3(640), dim3(256), 0, stream>>>(qbf, epartial);
  k4_softmax<<<dim3(B_ * C_ / 4), dim3(256), 0, stream>>>(epartial, att);
  k5_pv<<<dim3(2048), dim3(256), 0, stream>>>(att, qT, gse, x, out);
}